// Round 4
// baseline (493.260 us; speedup 1.0000x reference)
//
#include <hip/hip_runtime.h>
#include <stdint.h>

#define T_STEPS 512
#define CELLS   4096            // 64*64
#define BPB     4               // batches per block (per wave)
#define THREADS 64

// cell codes: 2 = goal (g==10, priority), 1 = wall (w==1 && !goal), 0 = free
__device__ __forceinline__ uint32_t pack4(float4 w, float4 g) {
    uint32_t b0 = (g.x == 10.0f) ? 2u : ((w.x == 1.0f) ? 1u : 0u);
    uint32_t b1 = (g.y == 10.0f) ? 2u : ((w.y == 1.0f) ? 1u : 0u);
    uint32_t b2 = (g.z == 10.0f) ? 2u : ((w.z == 1.0f) ? 1u : 0u);
    uint32_t b3 = (g.w == 10.0f) ? 2u : ((w.w == 1.0f) ? 1u : 0u);
    return b0 | (b1 << 8) | (b2 << 16) | (b3 << 24);
}

__global__ __launch_bounds__(THREADS) void rollout_kernel(
    const float* __restrict__ s0,
    const int*   __restrict__ act,
    const float* __restrict__ world,
    float* __restrict__ out,
    int B)
{
    __shared__ uint8_t cells[BPB * CELLS];   // 16 KiB -> 8+ blocks/CU resident

    const int tid = threadIdx.x;
    const int b0  = blockIdx.x * BPB;

    // ---- Phase 1: stage 4 batches' worlds, packed to bytes, into LDS ----
    #pragma unroll
    for (int bb = 0; bb < BPB; ++bb) {
        const float* wbase = world + (size_t)(b0 + bb) * (2 * CELLS);
        const float* gbase = wbase + CELLS;
        #pragma unroll
        for (int h = 0; h < 4; ++h) {
            const int c0 = h * 1024 + tid * 16;
            float4 w0 = *(const float4*)(wbase + c0);
            float4 w1 = *(const float4*)(wbase + c0 + 4);
            float4 w2 = *(const float4*)(wbase + c0 + 8);
            float4 w3 = *(const float4*)(wbase + c0 + 12);
            float4 g0 = *(const float4*)(gbase + c0);
            float4 g1 = *(const float4*)(gbase + c0 + 4);
            float4 g2 = *(const float4*)(gbase + c0 + 8);
            float4 g3 = *(const float4*)(gbase + c0 + 12);
            uint4 v = make_uint4(pack4(w0, g0), pack4(w1, g1),
                                 pack4(w2, g2), pack4(w3, g3));
            *(uint4*)(&cells[bb * CELLS + c0]) = v;
        }
    }
    __syncthreads();   // 1-wave block: compiles to the needed lgkmcnt drain

    // ---- Phase 2: lanes 0..3 each roll out one batch from LDS ----
    if (tid < BPB) {
        const int b = b0 + tid;
        float2 s = *(const float2*)(s0 + 2 * (size_t)b);
        int r = (int)s.x;
        int c = (int)s.y;
        int p = r * 64 + c;                       // flat index, as reference
        const uint8_t* my = cells + tid * CELLS;

        // lookup semantics (verified R3): negative idx wraps (+4096,
        // NumPy-style normalization), then mode='fill' (NaN) for anything
        // still OOB -> behaves as free cell (code 0).
        auto lookup = [&](int q) -> int {
            const int idx = q + ((q < 0) ? CELLS : 0);
            const int cell = my[idx & (CELLS - 1)];
            return ((unsigned)idx < (unsigned)CELLS) ? cell : 0;
        };

        float* s_out = out + (size_t)b * (2 * (T_STEPS + 1));
        float* r_out = out + (size_t)B * (2 * (T_STEPS + 1)) + (size_t)b * (T_STEPS + 1);

        *(float2*)s_out = s;                      // s_full[:,0] = s0
        r_out[0] = 0.0f;                          // r_full[:,0] = 0

        const int4* ap = (const int4*)(act + (size_t)b * T_STEPS);
        int4 A0 = ap[0];
        int4 A1 = ap[1];
        int4 A2 = ap[2];
        for (int k = 0; k < T_STEPS / 4; ++k) {
            const int4 A3 = (k + 3 < T_STEPS / 4) ? ap[k + 3] : A0;  // prefetch 12 steps ahead
            const int as4[4] = {A0.x, A0.y, A0.z, A0.w};
            #pragma unroll
            for (int jj = 0; jj < 2; ++jj) {      // two speculative 2-step rounds
                const int t  = k * 4 + jj * 2;
                const int a0 = as4[2 * jj];
                const int a1 = as4[2 * jj + 1];
                // deltas: 1 -> r-1, 2 -> r+1, 3 -> c-1, 4 -> c+1, 0 -> stay
                const int d0r = (a0 == 1) ? -1 : ((a0 == 2) ? 1 : 0);
                const int d0c = (a0 == 3) ? -1 : ((a0 == 4) ? 1 : 0);
                const int d1r = (a1 == 1) ? -1 : ((a1 == 2) ? 1 : 0);
                const int d1c = (a1 == 3) ? -1 : ((a1 == 4) ? 1 : 0);
                const int e0 = d0r * 64 + d0c;
                const int e1 = d1r * 64 + d1c;
                // speculative probes: step t from p; step t+1 from either
                // outcome {p, p+e0}. All 3 ds_reads issue before one wait.
                const int q0  = p + e0;
                const int q10 = p + e1;
                const int q11 = q0 + e1;
                const int l0  = lookup(q0);
                const int l10 = lookup(q10);
                const int l11 = lookup(q11);
                // resolve step t
                const bool hw0  = (l0 == 1);
                const float rew0 = (l0 == 2) ? 1.0f : (hw0 ? -1.0f : -0.01f);
                const int p0  = hw0 ? p : q0;
                const int r0v = hw0 ? r : r + d0r;
                const int c0v = hw0 ? c : c + d0c;
                // resolve step t+1 from the matching speculative read
                const int l1 = hw0 ? l10 : l11;
                const bool hw1  = (l1 == 1);
                const float rew1 = (l1 == 2) ? 1.0f : (hw1 ? -1.0f : -0.01f);
                p = hw1 ? p0 : p0 + e1;
                r = hw1 ? r0v : r0v + d1r;
                c = hw1 ? c0v : c0v + d1c;
                *(float2*)(s_out + 2 * (t + 1)) = make_float2((float)r0v, (float)c0v);
                *(float2*)(s_out + 2 * (t + 2)) = make_float2((float)r, (float)c);
                r_out[t + 1] = rew0;
                r_out[t + 2] = rew1;
            }
            A0 = A1; A1 = A2; A2 = A3;
        }
    }
}

extern "C" void kernel_launch(void* const* d_in, const int* in_sizes, int n_in,
                              void* d_out, int out_size, void* d_ws, size_t ws_size,
                              hipStream_t stream) {
    const float* s0    = (const float*)d_in[0];
    const int*   act   = (const int*)d_in[1];
    const float* world = (const float*)d_in[2];
    float*       out   = (float*)d_out;

    const int B = in_sizes[0] / 2;           // 8192
    const int grid = B / BPB;                // 2048 blocks, all resident

    rollout_kernel<<<grid, THREADS, 0, stream>>>(s0, act, world, out, B);
}

// Round 5
// 461.849 us; speedup vs baseline: 1.0680x; 1.0680x over previous
//
#include <hip/hip_runtime.h>
#include <stdint.h>

#define T_STEPS 512
#define CELLS   4096            // 64*64
#define EPB     32              // envs per rollout block (1 env per lane)
#define WPE     256             // packed words per env (4096 cells / 16 cells-per-word)
#define WPAD    257             // LDS stride (odd -> conflict-free same-word reads)

// ---- Kernel 1: pack world (float walls+goals) to 2-bit codes in d_ws ----
// code: 2 = goal (g==10, priority), 1 = wall (w==1 && !goal), 0 = free
__device__ __forceinline__ uint32_t code4(float4 w, float4 g) {
    uint32_t b0 = (g.x == 10.0f) ? 2u : ((w.x == 1.0f) ? 1u : 0u);
    uint32_t b1 = (g.y == 10.0f) ? 2u : ((w.y == 1.0f) ? 1u : 0u);
    uint32_t b2 = (g.z == 10.0f) ? 2u : ((w.z == 1.0f) ? 1u : 0u);
    uint32_t b3 = (g.w == 10.0f) ? 2u : ((w.w == 1.0f) ? 1u : 0u);
    return b0 | (b1 << 2) | (b2 << 4) | (b3 << 6);   // 4 cells x 2 bits
}

__global__ __launch_bounds__(64) void pack_kernel(
    const float* __restrict__ world, uint32_t* __restrict__ packed)
{
    const int b = blockIdx.x;
    const int t = threadIdx.x;
    const float* wbase = world + (size_t)b * (2 * CELLS);
    const float* gbase = wbase + CELLS;
    #pragma unroll
    for (int h = 0; h < 4; ++h) {
        const int w  = h * 64 + t;     // word index, 16 cells per word
        const int c0 = w * 16;
        uint32_t word = 0;
        #pragma unroll
        for (int j = 0; j < 4; ++j) {
            float4 wf = *(const float4*)(wbase + c0 + 4 * j);
            float4 gf = *(const float4*)(gbase + c0 + 4 * j);
            word |= code4(wf, gf) << (8 * j);
        }
        packed[(size_t)b * WPE + w] = word;
    }
}

// ---- Kernel 2: lane-dense rollout, 1 env per lane, worlds 2-bit in LDS ----
__global__ __launch_bounds__(64) void rollout_kernel(
    const float* __restrict__ s0,
    const int*   __restrict__ act,
    const uint32_t* __restrict__ packed,
    float* __restrict__ out,
    int B)
{
    __shared__ uint32_t lds[EPB * WPAD];   // 32896 B

    const int tid = threadIdx.x;
    const int b0  = blockIdx.x * EPB;

    // stage 32 envs' packed worlds (32 KB) from global into padded LDS
    for (int ee = 0; ee < EPB; ++ee) {
        uint4 v = *(const uint4*)(packed + (size_t)(b0 + ee) * WPE + tid * 4);
        const int base = ee * WPAD + tid * 4;
        lds[base]     = v.x;
        lds[base + 1] = v.y;
        lds[base + 2] = v.z;
        lds[base + 3] = v.w;
    }
    __syncthreads();

    if (tid < EPB) {
        const int b = b0 + tid;
        float2 s = *(const float2*)(s0 + 2 * (size_t)b);
        int r = (int)s.x;
        int c = (int)s.y;
        int p = r * 64 + c;                     // flat index, as reference
        const uint32_t* my = lds + tid * WPAD;

        // semantics (verified R3/R4, absmax 0): negative idx wraps (+4096,
        // NumPy normalization), then mode='fill' (NaN) for remaining OOB
        // -> acts as free cell (code 0).
        auto lookup = [&](int q) -> int {
            const int idx = q + ((q < 0) ? CELLS : 0);
            const uint32_t wd = my[(idx >> 4) & (WPE - 1)];
            const int cell = (wd >> ((idx & 15) * 2)) & 3;
            return ((unsigned)idx < (unsigned)CELLS) ? cell : 0;
        };

        float* s_out = out + (size_t)b * (2 * (T_STEPS + 1));
        float* r_out = out + (size_t)B * (2 * (T_STEPS + 1)) + (size_t)b * (T_STEPS + 1);

        *(float2*)s_out = s;                    // s_full[:,0] = s0
        r_out[0] = 0.0f;                        // r_full[:,0] = 0

        const int4* ap = (const int4*)(act + (size_t)b * T_STEPS);
        int4 A0 = ap[0];
        int4 A1 = ap[1];
        int4 A2 = ap[2];
        for (int k = 0; k < T_STEPS / 4; ++k) {
            const int4 A3 = (k + 3 < T_STEPS / 4) ? ap[k + 3] : A0;  // 12 steps ahead
            const int as4[4] = {A0.x, A0.y, A0.z, A0.w};
            #pragma unroll
            for (int jj = 0; jj < 2; ++jj) {    // two speculative 2-step rounds
                const int t  = k * 4 + jj * 2;
                const int a0 = as4[2 * jj];
                const int a1 = as4[2 * jj + 1];
                // deltas: 1 -> r-1, 2 -> r+1, 3 -> c-1, 4 -> c+1, 0 -> stay
                const int d0r = (a0 == 1) ? -1 : ((a0 == 2) ? 1 : 0);
                const int d0c = (a0 == 3) ? -1 : ((a0 == 4) ? 1 : 0);
                const int d1r = (a1 == 1) ? -1 : ((a1 == 2) ? 1 : 0);
                const int d1c = (a1 == 3) ? -1 : ((a1 == 4) ? 1 : 0);
                const int e0 = d0r * 64 + d0c;
                const int e1 = d1r * 64 + d1c;
                // speculative probes: step t from p; step t+1 from {p, p+e0}
                const int q0  = p + e0;
                const int q10 = p + e1;
                const int q11 = q0 + e1;
                const int l0  = lookup(q0);
                const int l10 = lookup(q10);
                const int l11 = lookup(q11);
                // resolve step t
                const bool hw0  = (l0 == 1);
                const float rew0 = (l0 == 2) ? 1.0f : (hw0 ? -1.0f : -0.01f);
                const int p0  = hw0 ? p : q0;
                const int r0v = hw0 ? r : r + d0r;
                const int c0v = hw0 ? c : c + d0c;
                // resolve step t+1 from the matching speculative read
                const int l1 = hw0 ? l10 : l11;
                const bool hw1  = (l1 == 1);
                const float rew1 = (l1 == 2) ? 1.0f : (hw1 ? -1.0f : -0.01f);
                p = hw1 ? p0 : p0 + e1;
                r = hw1 ? r0v : r0v + d1r;
                c = hw1 ? c0v : c0v + d1c;
                *(float2*)(s_out + 2 * (t + 1)) = make_float2((float)r0v, (float)c0v);
                *(float2*)(s_out + 2 * (t + 2)) = make_float2((float)r, (float)c);
                r_out[t + 1] = rew0;
                r_out[t + 2] = rew1;
            }
            A0 = A1; A1 = A2; A2 = A3;
        }
    }
}

extern "C" void kernel_launch(void* const* d_in, const int* in_sizes, int n_in,
                              void* d_out, int out_size, void* d_ws, size_t ws_size,
                              hipStream_t stream) {
    const float* s0    = (const float*)d_in[0];
    const int*   act   = (const int*)d_in[1];
    const float* world = (const float*)d_in[2];
    float*       out   = (float*)d_out;
    uint32_t*    packed = (uint32_t*)d_ws;     // needs B*256*4 = 8 MiB

    const int B = in_sizes[0] / 2;             // 8192

    pack_kernel<<<B, 64, 0, stream>>>(world, packed);
    rollout_kernel<<<B / EPB, 64, 0, stream>>>(s0, act, packed, out, B);
}